// Round 5
// baseline (103.307 us; speedup 1.0000x reference)
//
#include <hip/hip_runtime.h>
#include <math.h>

typedef unsigned int u32;
typedef _Float16 h8 __attribute__((ext_vector_type(8)));
typedef float f32x4 __attribute__((ext_vector_type(4)));

__device__ __forceinline__ u32 pkrtz(float x, float y){
    return __builtin_bit_cast(u32, __builtin_amdgcn_cvt_pkrtz(x, y));
}

// async global->LDS, 16B per lane; lds_uni must be wave-uniform (lane i lands at +16i)
__device__ __forceinline__ void stage16(const float* g4, u32* lds_uni){
#if __has_builtin(__builtin_amdgcn_global_load_lds)
    __builtin_amdgcn_global_load_lds((const __attribute__((address_space(1))) void*)g4,
                                     (__attribute__((address_space(3))) void*)lds_uni,
                                     16, 0, 0);
#else
    const int lane = threadIdx.x & 63;
    *(float4*)((float*)lds_uni + 4*lane) = *(const float4*)g4;
#endif
}

// 512 blocks (32 bn x 16 bm), tile 32n x 64m. 512 threads = 4 k-split groups x 128.
// Group g: k in [128g, 128g+128), 4 chunks of 32 k. LDS f32 row-major [row][32k],
// quad-swizzled on the GLOBAL side: LDS[row][c] = global[row][c ^ ((row>>2)&7)]
// -> hot-loop ds_read_b128 conflict-free, global_load_lds keeps its linear lane map.
// Hot loop: 4x4 micro-tile, 2 f32 ops/pair-k (sub + add-with-abs-modifier).
// dp on MFMA pipe (f16 frags pkrtz'd from LDS); l2^2 = nz + np - 2dp (f32 norms).
__global__ __launch_bounds__(512, 4) void fused_kernel(const float* __restrict__ z,
                                                       const float* __restrict__ zpr,
                                                       float* __restrict__ out){
    __shared__ u32 smem[17024];   // 68.1 KB: staging 4x3072 | overlay dpb/l1b/nzb

    const int t    = threadIdx.x;
    const int lane = t & 63;
    const int g    = t >> 7;        // k-split group 0..3
    const int q    = t & 127;       // thread within group
    const int w2   = (t >> 6) & 1;  // wave within group

    const int bn = blockIdx.x & 31;
    const int bm = blockIdx.x >> 5;
    const int n_base = bn * 32, m_base = bm * 64;

    u32*   stg = smem + g * 3072;
    float* zf  = (float*)stg;            // [32 rows][32 k]
    float* pf  = (float*)(stg + 1024);   // [64 rows][32 k]

    const int tn = q & 7;     // n0 = 4*tn
    const int tm = q >> 3;    // m0 = 4*tm  (0..15)
    const int o    = lane >> 4;
    const int colm = lane & 15;

    // per-lane global staging pointers (6 DMA insts per wave per chunk)
    const float* gsrc[6];
#pragma unroll
    for (int j = 0; j < 6; ++j){
        int s = j*128 + w2*64 + lane;
        int row, c; const float* base;
        if (s < 256){ row = s >> 3; c = s & 7; base = z   + (size_t)(n_base + row) * 512; }
        else { int s2 = s - 256; row = s2 >> 3; c = s2 & 7; base = zpr + (size_t)(m_base + row) * 512; }
        gsrc[j] = base + g*128 + 4*(c ^ ((row >> 2) & 7));
    }

    float l1[4][4];
#pragma unroll
    for (int j = 0; j < 4; ++j)
#pragma unroll
        for (int i = 0; i < 4; ++i) l1[j][i] = 0.f;
    f32x4 dpacc[2][2];
    dpacc[0][0] = (f32x4)(0.f); dpacc[0][1] = (f32x4)(0.f);
    dpacc[1][0] = (f32x4)(0.f); dpacc[1][1] = (f32x4)(0.f);
    float nacc = 0.f;

    for (int ck = 0; ck < 4; ++ck){
        // issue async staging for this chunk
#pragma unroll
        for (int j = 0; j < 6; ++j)
            stage16(gsrc[j] + ck*32, stg + (j*128 + w2*64)*4);
        __syncthreads();   // drains vmcnt -> tiles ready

        // ---- dp via MFMA (issue first; runs on matrix pipe under the l1 VALU loop) ----
        {
            h8 af[2], bf[2];
#pragma unroll
            for (int nb = 0; nb < 2; ++nb){
                const int n = nb*16 + colm;
                const int swz = (n >> 2) & 7;
                const float* rp = zf + n*32;
                float4 a0 = *(const float4*)(rp + 4*((2*o)   ^ swz));
                float4 a1 = *(const float4*)(rp + 4*((2*o+1) ^ swz));
                uint4 u = make_uint4(pkrtz(a0.x,a0.y), pkrtz(a0.z,a0.w),
                                     pkrtz(a1.x,a1.y), pkrtz(a1.z,a1.w));
                af[nb] = __builtin_bit_cast(h8, u);
            }
#pragma unroll
            for (int mb = 0; mb < 2; ++mb){
                const int m = (2*w2 + mb)*16 + colm;
                const int swz = (m >> 2) & 7;
                const float* rp = pf + m*32;
                float4 b0 = *(const float4*)(rp + 4*((2*o)   ^ swz));
                float4 b1 = *(const float4*)(rp + 4*((2*o+1) ^ swz));
                uint4 u = make_uint4(pkrtz(b0.x,b0.y), pkrtz(b0.z,b0.w),
                                     pkrtz(b1.x,b1.y), pkrtz(b1.z,b1.w));
                bf[mb] = __builtin_bit_cast(h8, u);
            }
#pragma unroll
            for (int nb = 0; nb < 2; ++nb)
#pragma unroll
                for (int mb = 0; mb < 2; ++mb)
                    dpacc[nb][mb] = __builtin_amdgcn_mfma_f32_16x16x32_f16(af[nb], bf[mb], dpacc[nb][mb], 0, 0, 0);
        }

        // ---- l1 hot loop: 8 k-quads, 16 pairs x 4k each ----
#pragma unroll 2
        for (int kq = 0; kq < 8; ++kq){
            float4 a[4], b[4];
#pragma unroll
            for (int i = 0; i < 4; ++i)
                a[i] = *(const float4*)(zf + (4*tn+i)*32 + 4*(kq ^ tn));
#pragma unroll
            for (int j = 0; j < 4; ++j)
                b[j] = *(const float4*)(pf + (4*tm+j)*32 + 4*(kq ^ (tm & 7)));
#pragma unroll
            for (int j = 0; j < 4; ++j)
#pragma unroll
                for (int i = 0; i < 4; ++i){
                    l1[j][i] += fabsf(a[i].x - b[j].x);
                    l1[j][i] += fabsf(a[i].y - b[j].y);
                    l1[j][i] += fabsf(a[i].z - b[j].z);
                    l1[j][i] += fabsf(a[i].w - b[j].w);
                }
        }

        // ---- norm mini-pass (f32, from staged tiles) ----
        if (q < 96){
            const int row = (q < 32) ? q : (q - 32);
            const float* rp2 = (q < 32) ? (zf + row*32) : (pf + row*32);
#pragma unroll
            for (int c = 0; c < 8; ++c){
                float4 v = *(const float4*)(rp2 + 4*((c + row) & 7));
                nacc += v.x*v.x + v.y*v.y + v.z*v.z + v.w*v.w;
            }
        }
        __syncthreads();
    }

    // ---- epilogue: overlay LDS, cross-group reduce ----
    float* dpb = (float*)smem;              // [4][32*66]
    float* l1b = (float*)(smem + 8448);     // [4][2048]
    float* nzb = (float*)(smem + 16640);    // [4][96] (0..31 z-rows, 32..95 p-rows)

#pragma unroll
    for (int nb = 0; nb < 2; ++nb)
#pragma unroll
        for (int mb = 0; mb < 2; ++mb){
            const int m = (2*w2 + mb)*16 + colm;
#pragma unroll
            for (int r = 0; r < 4; ++r){
                const int n = nb*16 + o*4 + r;
                dpb[g*2112 + n*66 + m] = dpacc[nb][mb][r];
            }
        }
#pragma unroll
    for (int j = 0; j < 4; ++j)
        *(float4*)&l1b[g*2048 + q*16 + j*4] = make_float4(l1[j][0], l1[j][1], l1[j][2], l1[j][3]);
    if (q < 96) nzb[g*96 + q] = nacc;
    __syncthreads();

    // ---- final: 512 threads cover all 2048 cells (4 each), write out ----
    {
        const int tn2 = t & 7;          // n-quad
        const int m   = t >> 3;         // 0..63
        const int qown = (m >> 2)*8 + tn2;
        const int idx  = (m & 3)*4;

        float l1o[4] = {0,0,0,0};
        float dp4[4] = {0,0,0,0};
        float nz4[4] = {0,0,0,0};
        float npv = 0.f;
#pragma unroll
        for (int gg = 0; gg < 4; ++gg){
            float4 p = *(const float4*)&l1b[gg*2048 + qown*16 + idx];
            l1o[0] += p.x; l1o[1] += p.y; l1o[2] += p.z; l1o[3] += p.w;
#pragma unroll
            for (int i = 0; i < 4; ++i)
                dp4[i] += dpb[gg*2112 + (4*tn2+i)*66 + m];
            float4 nzq = *(const float4*)&nzb[gg*96 + 4*tn2];
            nz4[0] += nzq.x; nz4[1] += nzq.y; nz4[2] += nzq.z; nz4[3] += nzq.w;
            npv += nzb[gg*96 + 32 + m];
        }
        float l2o[4];
#pragma unroll
        for (int i = 0; i < 4; ++i)
            l2o[i] = sqrtf(fmaxf(nz4[i] + npv - 2.f*dp4[i], 0.f));

        float* op = out + (((size_t)(m_base + m)) * 1024 + (n_base + 4*tn2)) * 3;
        ((float4*)op)[0] = make_float4(l1o[0], l2o[0], dp4[0], l1o[1]);
        ((float4*)op)[1] = make_float4(l2o[1], dp4[1], l1o[2], l2o[2]);
        ((float4*)op)[2] = make_float4(dp4[2], l1o[3], l2o[3], dp4[3]);
    }
}

extern "C" void kernel_launch(void* const* d_in, const int* in_sizes, int n_in,
                              void* d_out, int out_size, void* d_ws, size_t ws_size,
                              hipStream_t stream) {
    const float* z   = (const float*)d_in[0];
    const float* zpr = (const float*)d_in[1];
    float* out = (float*)d_out;
    fused_kernel<<<512, 512, 0, stream>>>(z, zpr, out);
}

// Round 6
// 78.807 us; speedup vs baseline: 1.3109x; 1.3109x over previous
//
#include <hip/hip_runtime.h>
#include <math.h>

typedef unsigned int u32;
typedef unsigned short u16;
typedef unsigned char u8;
typedef _Float16 h8v __attribute__((ext_vector_type(8)));
typedef float f32x4 __attribute__((ext_vector_type(4)));

__device__ __forceinline__ u32 sad8(u32 a, u32 b, u32 c){
#if __has_builtin(__builtin_amdgcn_sad_u8)
    return __builtin_amdgcn_sad_u8(a, b, c);
#else
    u32 s = c;
#pragma unroll
    for (int k = 0; k < 4; ++k){
        int av = (int)((a >> (8*k)) & 255u), bv = (int)((b >> (8*k)) & 255u);
        s += (u32)(av > bv ? av - bv : bv - av);
    }
    return s;
#endif
}

__device__ __forceinline__ void stage16(const void* g, u32* l){
    __builtin_amdgcn_global_load_lds((const __attribute__((address_space(1))) u32*)g,
                                     (__attribute__((address_space(3))) u32*)l, 16, 0, 0);
}

// -------- pre-pass: q8 = round(16x+128) u8; h16 = f16(x) (RTE); norms = sum f16(x)^2
__global__ __launch_bounds__(512) void prep_kernel(const float* __restrict__ z,
                                                   const float* __restrict__ zpr,
                                                   u8* __restrict__ q8,
                                                   u16* __restrict__ h16,
                                                   float* __restrict__ norms){
    const int row  = blockIdx.x*8 + (threadIdx.x >> 6);   // one wave per row, 2048 rows
    const int lane = threadIdx.x & 63;
    const float* src = (row < 1024) ? (z + (size_t)row*512) : (zpr + (size_t)(row-1024)*512);
    float4 v0 = ((const float4*)src)[2*lane];
    float4 v1 = ((const float4*)src)[2*lane + 1];
    float xs[8] = {v0.x,v0.y,v0.z,v0.w,v1.x,v1.y,v1.z,v1.w};
    u32 b0 = 0, b1 = 0;
#pragma unroll
    for (int k = 0; k < 4; ++k){
        b0 |= ((u32)fmaf(xs[k],   16.f, 128.5f) & 255u) << (8*k);
        b1 |= ((u32)fmaf(xs[4+k], 16.f, 128.5f) & 255u) << (8*k);
    }
    ((uint2*)(q8 + (size_t)row*512))[lane] = make_uint2(b0, b1);
    u32 hw[4]; float s = 0.f;
#pragma unroll
    for (int k = 0; k < 4; ++k){
        _Float16 ha = (_Float16)xs[2*k], hb = (_Float16)xs[2*k+1];
        float fa = (float)ha, fb = (float)hb;
        s += fa*fa + fb*fb;
        hw[k] = (u32)__builtin_bit_cast(u16, ha) | ((u32)__builtin_bit_cast(u16, hb) << 16);
    }
    ((uint4*)(h16 + (size_t)row*512))[lane] = make_uint4(hw[0],hw[1],hw[2],hw[3]);
#pragma unroll
    for (int off = 32; off > 0; off >>= 1) s += __shfl_down(s, off);
    if (lane == 0) norms[row] = s;
}

// -------- main: 256 blocks (16x16), tile 64n x 64m, 512 thr.
// LDS staging (double-buffered): per buf, per k-group g: u8 tile [128 rows][32k] (1024 w)
// + f16 tile [128][32k] (2048 w). 8 chunk-iters of 32k; sad groups g=t>>8 split K 2-way.
// Hot loop: 4x4 micro, v_sad_u8 = 0.25 VALU op / pair-k. dp: each wave owns 2 MFMA
// tiles over FULL K (reads both groups' f16 tiles) -> no dp cross-group reduce.
// Swizzles (8-lane phase-group model): u8 reads c^((row>>2)&1) with rows tn+16i
// (conflict-free); b-loads broadcast; f16 frags c^((row>>1)&3) (conflict-free).
__global__ __launch_bounds__(512, 2) void fused_kernel(const u8* __restrict__ q8,
                                                       const u16* __restrict__ h16,
                                                       const float* __restrict__ norms,
                                                       float* __restrict__ out){
    __shared__ u32 smem[12544];   // 50 KB: staging 2x6144 | epilogue dpb 4224 + l1b 8192

    const int t = threadIdx.x;
    const int lane = t & 63;
    const int w = t >> 6;
    const int g = t >> 8;          // sad k-group: k in [256g, 256g+256)
    const int q = t & 255;
    const int tn = q & 15, tm = q >> 4;
    const int bn = blockIdx.x & 15, bm = blockIdx.x >> 4;
    const int n_base = bn*64, m_base = bm*64;
    const int colm = lane & 15, o = lane >> 4;

    // ---- 3 DMA descriptors per wave (24 per block-chunk: u8 4+4, f16 8+8) ----
    const u8* gsrc[3];
    int ldst[3], step[3];
#pragma unroll
    for (int j = 0; j < 3; ++j){
        const int e = w*3 + j;
        if (e < 8){
            const int gg = e >> 2;
            const int rb = 32*(e & 3);
            const int trow = rb + (lane >> 1);
            const int c = lane & 1;
            const int grow = (trow < 64) ? (n_base + trow) : (1024 + m_base + trow - 64);
            gsrc[j] = q8 + (size_t)grow*512 + gg*256 + 16*(c ^ ((trow >> 2) & 1));
            ldst[j] = gg*3072 + rb*8;
            step[j] = 32;
        } else {
            const int e2 = e - 8;
            const int gg = e2 >> 3;
            const int rb = 16*(e2 & 7);
            const int trow = rb + (lane >> 2);
            const int c = lane & 3;
            const int grow = (trow < 64) ? (n_base + trow) : (1024 + m_base + trow - 64);
            gsrc[j] = (const u8*)h16 + (size_t)grow*1024 + gg*512 + 16*(c ^ ((trow >> 1) & 3));
            ldst[j] = gg*3072 + 1024 + rb*16;
            step[j] = 64;
        }
    }

    u32 acc[4][4] = {{0u}};
    f32x4 dpacc[2]; dpacc[0] = (f32x4)(0.f); dpacc[1] = (f32x4)(0.f);
    const int nbw = w & 3;             // wave's MFMA n-block
    const int mb0 = 2*(w >> 2);        // wave's MFMA m-block pair
    const int arow  = nbw*16 + colm;
    const int aoff  = arow*16 + 4*(o ^ ((arow >> 1) & 3));
    const int brow0 = 64 + (mb0    )*16 + colm;
    const int brow1 = 64 + (mb0 + 1)*16 + colm;
    const int boff0 = brow0*16 + 4*(o ^ ((brow0 >> 1) & 3));
    const int boff1 = brow1*16 + 4*(o ^ ((brow1 >> 1) & 3));

#pragma unroll
    for (int j = 0; j < 3; ++j) stage16(gsrc[j], smem + ldst[j]);
    __syncthreads();

    for (int ck = 0; ck < 8; ++ck){
        u32* stg = smem + (ck & 1)*6144;
        if (ck < 7){
#pragma unroll
            for (int j = 0; j < 3; ++j)
                stage16(gsrc[j] + (size_t)(ck+1)*step[j], smem + ((ck+1)&1)*6144 + ldst[j]);
        }

        // ---- dp on MFMA pipe: this wave's 2 tiles, both k-groups' 32k ----
#pragma unroll
        for (int gb = 0; gb < 2; ++gb){
            const u32* f16t = stg + gb*3072 + 1024;
            h8v af = __builtin_bit_cast(h8v, *(const uint4*)(f16t + aoff));
            h8v bf0 = __builtin_bit_cast(h8v, *(const uint4*)(f16t + boff0));
            h8v bf1 = __builtin_bit_cast(h8v, *(const uint4*)(f16t + boff1));
            dpacc[0] = __builtin_amdgcn_mfma_f32_16x16x32_f16(af, bf0, dpacc[0], 0, 0, 0);
            dpacc[1] = __builtin_amdgcn_mfma_f32_16x16x32_f16(af, bf1, dpacc[1], 0, 0, 0);
        }

        // ---- l1 sad loop: group g's 32k, 4x4 micro (rows tn+16i / 64+tm+16j) ----
        const u32* u8t = stg + g*3072;
#pragma unroll
        for (int kq = 0; kq < 2; ++kq){
            uint4 av[4], bv[4];
#pragma unroll
            for (int i = 0; i < 4; ++i){
                const int ar = tn + 16*i;
                av[i] = *(const uint4*)(u8t + ar*8 + 4*(kq ^ ((ar >> 2) & 1)));
            }
#pragma unroll
            for (int j2 = 0; j2 < 4; ++j2){
                const int br = 64 + tm + 16*j2;
                bv[j2] = *(const uint4*)(u8t + br*8 + 4*(kq ^ ((br >> 2) & 1)));
            }
#pragma unroll
            for (int i = 0; i < 4; ++i)
#pragma unroll
                for (int j2 = 0; j2 < 4; ++j2){
                    u32 s = acc[i][j2];
                    s = sad8(av[i].x, bv[j2].x, s);
                    s = sad8(av[i].y, bv[j2].y, s);
                    s = sad8(av[i].z, bv[j2].z, s);
                    s = sad8(av[i].w, bv[j2].w, s);
                    acc[i][j2] = s;
                }
        }
        __syncthreads();
    }

    // ---- epilogue: dp + l1 partials to LDS, redistribute for coalesced output ----
    float* dpb = (float*)smem;            // [64][66]
    float* l1b = (float*)(smem + 4224);   // [512][16]
#pragma unroll
    for (int tt = 0; tt < 2; ++tt){
        const int m = (mb0 + tt)*16 + colm;
#pragma unroll
        for (int r = 0; r < 4; ++r)
            dpb[(nbw*16 + o*4 + r)*66 + m] = dpacc[tt][r];
    }
#pragma unroll
    for (int i = 0; i < 4; ++i)
        *(float4*)&l1b[t*16 + i*4] = make_float4((float)acc[i][0], (float)acc[i][1],
                                                 (float)acc[i][2], (float)acc[i][3]);
    __syncthreads();

    const int mo = t >> 3;                 // output m 0..63
    const int n0 = 8*(t & 7);              // output n block
    const float np = norms[1024 + m_base + mo];
    const int qpb = (mo & 15)*16;
    const int jp  = mo >> 4;
    float ov[24];
#pragma unroll
    for (int i = 0; i < 8; ++i){
        const int n = n0 + i;
        const int qp = qpb + (n & 15);
        const int idx = (n >> 4)*4 + jp;
        const float l1v = (l1b[qp*16 + idx] + l1b[(256 + qp)*16 + idx]) * (1.f/16.f);
        const float dp = dpb[n*66 + mo];
        const float nz = norms[n_base + n];
        const float l2 = sqrtf(fmaxf(nz + np - 2.f*dp, 0.f));
        ov[3*i] = l1v; ov[3*i+1] = l2; ov[3*i+2] = dp;
    }
    float4* op = (float4*)(out + ((size_t)(m_base + mo)*1024 + n_base + n0)*3);
#pragma unroll
    for (int k = 0; k < 6; ++k)
        op[k] = make_float4(ov[4*k], ov[4*k+1], ov[4*k+2], ov[4*k+3]);
}

extern "C" void kernel_launch(void* const* d_in, const int* in_sizes, int n_in,
                              void* d_out, int out_size, void* d_ws, size_t ws_size,
                              hipStream_t stream) {
    const float* z   = (const float*)d_in[0];
    const float* zpr = (const float*)d_in[1];
    float* out = (float*)d_out;
    u8*  q8    = (u8*)d_ws;                                // 1 MB
    u16* h16   = (u16*)((char*)d_ws + (1 << 20));          // 2 MB
    float* nrm = (float*)((char*)d_ws + 3*(1 << 20));      // 8 KB

    prep_kernel<<<256, 512, 0, stream>>>(z, zpr, q8, h16, nrm);
    fused_kernel<<<256, 512, 0, stream>>>(q8, h16, nrm, out);
}

// Round 9
// 70.674 us; speedup vs baseline: 1.4617x; 1.1151x over previous
//
#include <hip/hip_runtime.h>
#include <math.h>

typedef unsigned int u32;
typedef unsigned short u16;
typedef unsigned char u8;
typedef int i32x4 __attribute__((ext_vector_type(4)));
typedef int i32x16 __attribute__((ext_vector_type(16)));

#if __has_builtin(__builtin_amdgcn_mfma_i32_32x32x32_i8)
#define HAS_MFMA_I8 1
#else
#define HAS_MFMA_I8 0
#endif

__device__ __forceinline__ u32 sad8(u32 a, u32 b, u32 c){
#if __has_builtin(__builtin_amdgcn_sad_u8)
    return __builtin_amdgcn_sad_u8(a, b, c);
#else
    u32 s = c;
#pragma unroll
    for (int k = 0; k < 4; ++k){
        int av = (int)((a >> (8*k)) & 255u), bv = (int)((b >> (8*k)) & 255u);
        s += (u32)(av > bv ? av - bv : bv - av);
    }
    return s;
#endif
}

__device__ __forceinline__ u32 hsum16(u32 x, u32 c){ return c + (x & 0xFFFFu) + (x >> 16); }

#if !HAS_MFMA_I8
__device__ __forceinline__ int sdot4(u32 a, u32 b, int c){
#if __has_builtin(__builtin_amdgcn_sdot4)
    return __builtin_amdgcn_sdot4((int)a, (int)b, c, false);
#else
    int s = c;
#pragma unroll
    for (int k = 0; k < 4; ++k){
        int av = (int)(signed char)((a >> (8*k)) & 255u);
        int bv = (int)(signed char)((b >> (8*k)) & 255u);
        s += av * bv;
    }
    return s;
#endif
}
#endif

// ---- prep: q8[row][512] = round(16x)+128 (u8); norms[row] = sum s8^2 (exact int in f32)
__global__ __launch_bounds__(512) void prep_kernel(const float* __restrict__ z,
                                                   const float* __restrict__ zpr,
                                                   u8* __restrict__ q8,
                                                   float* __restrict__ norms){
    const int row  = blockIdx.x*8 + (threadIdx.x >> 6);
    const int lane = threadIdx.x & 63;
    const float* src = (row < 1024) ? (z + (size_t)row*512) : (zpr + (size_t)(row-1024)*512);
    float4 v0 = ((const float4*)src)[2*lane];
    float4 v1 = ((const float4*)src)[2*lane + 1];
    float xs[8] = {v0.x,v0.y,v0.z,v0.w,v1.x,v1.y,v1.z,v1.w};
    u32 b0 = 0, b1 = 0; float s = 0.f;
#pragma unroll
    for (int k = 0; k < 4; ++k){
        u32 qa = (u32)fmaf(xs[k],   16.f, 128.5f) & 255u;
        u32 qb = (u32)fmaf(xs[4+k], 16.f, 128.5f) & 255u;
        b0 |= qa << (8*k);  b1 |= qb << (8*k);
        int sa = (int)qa - 128, sb = (int)qb - 128;
        s += (float)(sa*sa + sb*sb);
    }
    ((uint2*)(q8 + (size_t)row*512))[lane] = make_uint2(b0, b1);
#pragma unroll
    for (int off = 32; off > 0; off >>= 1) s += __shfl_down(s, off);
    if (lane == 0) norms[row] = s;
}

// ---- main: 512 blocks (32 bn x 16 bm), tile 32n x 64m, 512 thr = 8 waves.
// R9: NO global_load_lds, NO double-buffer (R8 diverged on graph replays —
// cross-wave DMA-consumption race class). Single phase: each wave stages its
// full 64-k slice (96 rows x 64 B) via uint4 loads + ds_write_b128, one
// barrier, all compute, one barrier, epilogue. All LDS deps register-tracked.
// Row stride 20 words (80 B, 16B-aligned): MFMA frag reads conflict-free,
// sad reads 2-way broadcast (free), ds_writes 2-way (free).
#define RS 20
#define L1S 520
__global__ __launch_bounds__(512, 4) void fused_kernel(const u8* __restrict__ q8,
                                                       const float* __restrict__ norms,
                                                       float* __restrict__ out){
    __shared__ u32 smem[15360];   // 61.4 KB: staging [8 waves][96 rows][20 w] / epilogue overlay
    const int t = threadIdx.x;
    const int lane = t & 63;
    const int w = t >> 6;
    const int bn = blockIdx.x & 31;
    const int bm = blockIdx.x >> 5;
    const int n_base = bn*32, m_base = bm*64;

    // ---- stage: wave w's k-slice [64w, 64w+64), 96 rows (32 z + 64 zpr) ----
    u32* wbase = smem + w*1920;
    {
        const int c = lane & 3;              // 16B column
        const int r4 = lane >> 2;            // row within 16-row group
#pragma unroll
        for (int j = 0; j < 6; ++j){
            const int rt = j*16 + r4;        // 0..95
            const int grow = (rt < 32) ? (n_base + rt) : (1024 + m_base + rt - 32);
            uint4 v = *(const uint4*)(q8 + (size_t)grow*512 + 64*w + 16*c);
            *(uint4*)(wbase + rt*RS + 4*c) = v;
        }
    }

    const int tn = lane & 3, tm = lane >> 2;
    u32 acc[8][4];
#pragma unroll
    for (int i = 0; i < 8; ++i)
#pragma unroll
        for (int j = 0; j < 4; ++j) acc[i][j] = 0u;

#if HAS_MFMA_I8
    i32x16 dpacc = (i32x16)(0);
    const int mt = w & 1;          // m-tile (32 cols) for waves 0-3
    const int kh = w >> 1;         // k-half group for waves 0-3
    const int arow = lane & 31;
    const int brow = 32 + mt*32 + (lane & 31);
    const int o1 = lane >> 5;
#else
    int dpa[8][4];
#pragma unroll
    for (int i = 0; i < 8; ++i)
#pragma unroll
        for (int j = 0; j < 4; ++j) dpa[i][j] = 0;
#endif

    __syncthreads();   // barrier #1: all tiles staged (lgkm-tracked ds_writes)

#if HAS_MFMA_I8
    if (w < 4){
#pragma unroll
        for (int s = 0; s < 4; ++s){
            const u32* gb = smem + (kh*4 + s)*1920;
#pragma unroll
            for (int h = 0; h < 2; ++h){
                uint4 a = *(const uint4*)(gb + arow*RS + 8*h + 4*o1);
                uint4 b = *(const uint4*)(gb + brow*RS + 8*h + 4*o1);
                uint4 ax = make_uint4(a.x^0x80808080u, a.y^0x80808080u, a.z^0x80808080u, a.w^0x80808080u);
                uint4 bx = make_uint4(b.x^0x80808080u, b.y^0x80808080u, b.z^0x80808080u, b.w^0x80808080u);
                dpacc = __builtin_amdgcn_mfma_i32_32x32x32_i8(__builtin_bit_cast(i32x4, ax),
                                                              __builtin_bit_cast(i32x4, bx),
                                                              dpacc, 0, 0, 0);
            }
        }
    }
#endif

    // ---- sad hot loop: wave w's 64 k, 8n x 4m micro ----
#pragma unroll
    for (int c = 0; c < 4; ++c){
        uint4 av[8], bv[4];
#pragma unroll
        for (int i = 0; i < 8; ++i)
            av[i] = *(const uint4*)(wbase + (tn + 4*i)*RS + 4*c);
#pragma unroll
        for (int j2 = 0; j2 < 4; ++j2)
            bv[j2] = *(const uint4*)(wbase + (32 + tm + 16*j2)*RS + 4*c);
#pragma unroll
        for (int i = 0; i < 8; ++i)
#pragma unroll
            for (int j2 = 0; j2 < 4; ++j2){
                u32 s = acc[i][j2];
                s = sad8(av[i].x, bv[j2].x, s);
                s = sad8(av[i].y, bv[j2].y, s);
                s = sad8(av[i].z, bv[j2].z, s);
                s = sad8(av[i].w, bv[j2].w, s);
                acc[i][j2] = s;
#if !HAS_MFMA_I8
                int d = dpa[i][j2];
                d = sdot4(av[i].x^0x80808080u, bv[j2].x^0x80808080u, d);
                d = sdot4(av[i].y^0x80808080u, bv[j2].y^0x80808080u, d);
                d = sdot4(av[i].z^0x80808080u, bv[j2].z^0x80808080u, d);
                d = sdot4(av[i].w^0x80808080u, bv[j2].w^0x80808080u, d);
                dpa[i][j2] = d;
#endif
            }
    }
    __syncthreads();   // barrier #2: all reads done; staging region now dead

    // ---- epilogue (overlays staging) ----
    u16*   l1b  = (u16*)smem;                  // [32 n][520] u16
    float* dpbA = (float*)(smem + 8320);       // [32][65]
    float* dpbB = (float*)(smem + 10400);      // [32][65]

#pragma unroll
    for (int i = 0; i < 8; ++i)
#pragma unroll
        for (int j = 0; j < 4; ++j)
            l1b[(tn + 4*i)*L1S + (tm + 16*j)*8 + w] = (u16)acc[i][j];

#if HAS_MFMA_I8
    if (w < 4){
        float* dpb = kh ? dpbB : dpbA;
        const int mcol = mt*32 + (lane & 31);
#pragma unroll
        for (int reg = 0; reg < 16; ++reg){
            const int n = (reg & 3) + 8*(reg >> 2) + 4*(lane >> 5);
            dpb[n*65 + mcol] = (float)dpacc[reg];
        }
    }
#endif
    __syncthreads();

    const int m  = t >> 3;
    const int n0 = 4*(t & 7);
    float4 nz4 = *(const float4*)&norms[n_base + n0];
    const float np = norms[1024 + m_base + m];
    const float nzv[4] = {nz4.x, nz4.y, nz4.z, nz4.w};

    float l1q[4], dpq[4];
#pragma unroll
    for (int i = 0; i < 4; ++i){
        const int n = n0 + i;
        uint4 lp = *(const uint4*)&l1b[n*L1S + m*8];
        u32 s = hsum16(lp.x, 0u); s = hsum16(lp.y, s);
        s = hsum16(lp.z, s);      s = hsum16(lp.w, s);
        l1q[i] = (float)s;
#if HAS_MFMA_I8
        dpq[i] = dpbA[n*65 + m] + dpbB[n*65 + m];
#else
        dpq[i] = 0.f;
#endif
    }

#if !HAS_MFMA_I8
    {
        float* dpf = (float*)(smem + 8320);   // [2048][2]
#pragma unroll
        for (int ph = 0; ph < 4; ++ph){
            __syncthreads();
            if ((w >> 1) == ph){
#pragma unroll
                for (int i = 0; i < 8; ++i)
#pragma unroll
                    for (int j = 0; j < 4; ++j)
                        dpf[((tn + 4*i)*64 + tm + 16*j)*2 + (w & 1)] = (float)dpa[i][j];
            }
            __syncthreads();
#pragma unroll
            for (int i = 0; i < 4; ++i){
                const int cell = (n0 + i)*64 + m;
                dpq[i] += dpf[cell*2] + dpf[cell*2 + 1];
            }
        }
    }
#endif

    float ov[12];
#pragma unroll
    for (int i = 0; i < 4; ++i){
        const float l2q = nzv[i] + np - 2.f*dpq[i];
        ov[3*i]     = l1q[i] * 0.0625f;
        ov[3*i + 1] = sqrtf(fmaxf(l2q, 0.f)) * 0.0625f;
        ov[3*i + 2] = dpq[i] * 0.00390625f;
    }
    float4* op = (float4*)(out + (((size_t)(m_base + m))*1024 + n_base + n0)*3);
    op[0] = make_float4(ov[0], ov[1], ov[2],  ov[3]);
    op[1] = make_float4(ov[4], ov[5], ov[6],  ov[7]);
    op[2] = make_float4(ov[8], ov[9], ov[10], ov[11]);
}

extern "C" void kernel_launch(void* const* d_in, const int* in_sizes, int n_in,
                              void* d_out, int out_size, void* d_ws, size_t ws_size,
                              hipStream_t stream) {
    const float* z   = (const float*)d_in[0];
    const float* zpr = (const float*)d_in[1];
    float* out = (float*)d_out;
    u8*    q8  = (u8*)d_ws;                            // 1 MB
    float* nrm = (float*)((char*)d_ws + (1 << 20));    // 8 KB

    prep_kernel<<<256, 512, 0, stream>>>(z, zpr, q8, nrm);
    fused_kernel<<<512, 512, 0, stream>>>(q8, nrm, out);
}